// Round 1
// 414.569 us; speedup vs baseline: 1.0121x; 1.0121x over previous
//
#include <hip/hip_runtime.h>
#include <cstdio>

// VQ nearest-codebook, round 5.
// vq_main rebuilt on the m201-style 256x256 / BK=64 / 8-wave phase-split
// schedule: 128B LDS rows + ((row&7)<<4) XOR swizzle (uniform banks),
// 4 phases x 16 MFMA per K-tile with raw s_barrier + lgkmcnt(0) + setprio
// clusters, all prefetch issued in phases 0-1 (A early = HBM latency,
// B late = L2-resident), vmcnt drain only at K-tile boundary with >=2-phase
// slack; prologue 2 tiles deep (vmcnt(8)).
// fp16 stage-1 + TAU 0.05 + exact fp64 refine of flagged + gather.

typedef float f32x4 __attribute__((ext_vector_type(4)));
typedef _Float16 half8 __attribute__((ext_vector_type(8)));

#define KDIM 512
#define NCODES 1024
#define NQ 65536
#define TAU_S 0.05f   // fp16 dot err sigma ~0.009; 0.05 ~ 5.5 sigma (passed R3, absmax 0)

// ---- workspace layout (bytes) ----
#define WS_XH    0ull                         // fp16 x [65536][512]      67108864
#define WS_CBH   67108864ull                  // fp16 cb [1024][512]       1048576
#define WS_C2H   68157440ull                  // float 0.5||c||^2 [1024]
#define WS_C2D   68161536ull                  // double 0.5||c||^2 [1024]
#define WS_CAND1 68169728ull                  // float [65536][4] (1 MB); +CAND2 reused as cbT
#define WS_CBT   WS_CAND1                     // fp32 cbT [512][1024] = 2 MB (spans CAND1+CAND2)
#define WS_CAND2 69218304ull                  // float [65536][4] (1 MB)
#define WS_CANDC 70266880ull                  // int   [65536][4] (1 MB)
#define WS_IDX   71315456ull                  // int   [65536]
#define WS_LIST  71577600ull                  // int   [65536]
#define WS_CTR   71839744ull                  // int
#define WS_NEED  (WS_CTR + 4ull)

__device__ __forceinline__ unsigned short f2h(float f) {
  _Float16 h = (_Float16)f;                   // RNE
  return __builtin_bit_cast(unsigned short, h);
}

__device__ __forceinline__ void async16(const void* g, void* l) {
  __builtin_amdgcn_global_load_lds(
      (const __attribute__((address_space(1))) void*)g,
      (__attribute__((address_space(3))) void*)l, 16, 0, 0);
}

// ---------------- prep: codebook -> fp16 row-major + 0.5||c||^2 ----------------
__global__ __launch_bounds__(256) void vq_prep(const float* __restrict__ cb,
                                               unsigned short* __restrict__ cbh,
                                               float* __restrict__ c2h,
                                               double* __restrict__ c2d) {
  int lane = threadIdx.x & 63;
  int row = blockIdx.x * 4 + (threadIdx.x >> 6);
  const float4* src = (const float4*)(cb + (size_t)row * KDIM);
  float4 u = src[lane * 2], v = src[lane * 2 + 1];
  double p = (double)u.x * u.x + (double)u.y * u.y + (double)u.z * u.z + (double)u.w * u.w +
             (double)v.x * v.x + (double)v.y * v.y + (double)v.z * v.z + (double)v.w * v.w;
#pragma unroll
  for (int m = 1; m < 64; m <<= 1) p += __shfl_xor(p, m);
  if (lane == 0) { c2h[row] = (float)(0.5 * p); c2d[row] = 0.5 * p; }
  unsigned r0 = f2h(u.x) | ((unsigned)f2h(u.y) << 16);
  unsigned r1 = f2h(u.z) | ((unsigned)f2h(u.w) << 16);
  unsigned r2 = f2h(v.x) | ((unsigned)f2h(v.y) << 16);
  unsigned r3 = f2h(v.z) | ((unsigned)f2h(v.w) << 16);
  *(int4*)(cbh + (size_t)row * KDIM + lane * 8) = make_int4((int)r0, (int)r1, (int)r2, (int)r3);
}

// ---------------- convx: x fp32 -> fp16 ----------------
__global__ __launch_bounds__(256) void vq_convx(const float4* __restrict__ x4,
                                                int4* __restrict__ xh4) {
  size_t t = (size_t)blockIdx.x * 256 + threadIdx.x;
  float4 u = x4[t * 2], v = x4[t * 2 + 1];
  unsigned r0 = f2h(u.x) | ((unsigned)f2h(u.y) << 16);
  unsigned r1 = f2h(u.z) | ((unsigned)f2h(u.w) << 16);
  unsigned r2 = f2h(v.x) | ((unsigned)f2h(v.y) << 16);
  unsigned r3 = f2h(v.z) | ((unsigned)f2h(v.w) << 16);
  xh4[t] = make_int4((int)r0, (int)r1, (int)r2, (int)r3);
}

// ---------------- main: 256x256 fp16 MFMA tile + fused argmin ----------------
// grid 1024 = 256 m-tiles x 4 n-tiles (nb = blk&3; XCD = blk&7 sees one nb ->
// its 256 KB B panel stays L2-resident; A shared across XCDs via L3).
// 512 thr / 8 waves as 2x4 of 128x64 wave tiles. BK=64, K=512 -> 8 K-tiles.
// LDS 128 KB: As[2][256][64], Bs[2][256][64], rows 128B, swizzle ((row&7)<<4).
#define PBAR __builtin_amdgcn_s_barrier()
#define SB0  __builtin_amdgcn_sched_barrier(0)
#define LGKM0 do { asm volatile("s_waitcnt lgkmcnt(0)" ::: "memory"); SB0; } while (0)

__global__ __launch_bounds__(512, 2) void vq_main(const unsigned short* __restrict__ xh,
                                                  const unsigned short* __restrict__ cbh,
                                                  const float* __restrict__ c2h,
                                                  float* __restrict__ cand1,
                                                  float* __restrict__ cand2,
                                                  int* __restrict__ candc) {
  __shared__ unsigned short lds[65536];        // 128 KB
  unsigned short* As = lds;                    // [2][256 rows][64 halfs] = 2x32KB
  unsigned short* Bs = lds + 32768;            // same, bytes 65536..131071
  float* red1 = (float*)lds;                   // epilogue alias (in As buf0)
  float* red2 = (float*)(lds + 2048);          // +4KB
  int*   redc = (int*)(lds + 4096);            // +8KB

  const int tid = threadIdx.x;
  const int lane = tid & 63, wv = tid >> 6;    // 8 waves
  const int mw = wv >> 2, nw = wv & 3;         // 2 x 4 wave grid
  const int c = lane & 15, q = lane >> 4;
  const int mb = blockIdx.x >> 2, nb = blockIdx.x & 3;

  // ---- staging geometry: thread covers 16B; row = h*128 + l*64 + (tid>>3).
  // LDS dest is linear; global source column is pre-swizzled with the same
  // involution the reads use: col ^= ((row&7)*8) halfs (rule 21).
  const int srow = tid >> 3;
  const int scol = ((tid & 7) ^ (srow & 7)) * 8;
  const unsigned short* ax[2][2];
  const unsigned short* bx[2][2];
#pragma unroll
  for (int h = 0; h < 2; ++h)
#pragma unroll
    for (int l = 0; l < 2; ++l) {
      int row = h * 128 + l * 64 + srow;
      ax[h][l] = xh  + (size_t)(mb * 256 + row) * KDIM + scol;
      bx[h][l] = cbh + (size_t)(nb * 256 + row) * KDIM + scol;
    }

#define STAGE_A(tt, h) do { \
    int _bo = ((tt) & 1) * 16384 + (h) * 8192 + tid * 8; \
    async16(ax[h][0] + (tt) * 64, &As[_bo]); \
    async16(ax[h][1] + (tt) * 64, &As[_bo + 4096]); } while (0)
#define STAGE_B(tt, h) do { \
    int _bo = ((tt) & 1) * 16384 + (h) * 8192 + tid * 8; \
    async16(bx[h][0] + (tt) * 64, &Bs[_bo]); \
    async16(bx[h][1] + (tt) * 64, &Bs[_bo + 4096]); } while (0)

  // ---- fragment-read geometry (swizzled): addr = row*64 + ((ks*32+q*8)^((c&7)*8))
  const int swz = (c & 7) * 8;
  const int acol0 = (q * 8) ^ swz;
  const int acol1 = acol0 ^ 32;
  const int aro = (mw * 128 + c) * 64;
  const int bro = (nw * 64 + c) * 64;
#define RDA(buf, i, ks) (*(const half8*)&As[(buf) * 16384 + aro + (i) * 1024 + ((ks) ? acol1 : acol0)])
#define RDB(buf, j, ks) (*(const half8*)&Bs[(buf) * 16384 + bro + (j) * 1024 + ((ks) ? acol1 : acol0)])

  f32x4 acc[8][4];
#pragma unroll
  for (int i = 0; i < 8; ++i)
#pragma unroll
    for (int j = 0; j < 4; ++j) acc[i][j] = (f32x4){0.f, 0.f, 0.f, 0.f};
  half8 a[4][2], b[4][2];

  // ---- prologue: stage tiles 0 and 1 (8 + 8 loads), wait tile 0 only ----
  STAGE_A(0, 0); STAGE_A(0, 1); STAGE_B(0, 0); STAGE_B(0, 1);
  STAGE_A(1, 0); STAGE_A(1, 1); STAGE_B(1, 0); STAGE_B(1, 1);
  asm volatile("s_waitcnt vmcnt(8)" ::: "memory");
  PBAR;

#pragma unroll
  for (int t = 0; t < 8; ++t) {
    const int cb = t & 1;
    // ---------- phase 0: a(i0-3), b(j0-1); stage A-h0 + B-h0 of tile t+1 ----------
#pragma unroll
    for (int ii = 0; ii < 4; ++ii) { a[ii][0] = RDA(cb, ii, 0); a[ii][1] = RDA(cb, ii, 1); }
#pragma unroll
    for (int j = 0; j < 2; ++j) { b[j][0] = RDB(cb, j, 0); b[j][1] = RDB(cb, j, 1); }
    if (t >= 1 && t < 7) { STAGE_A(t + 1, 0); STAGE_B(t + 1, 0); }
    PBAR; LGKM0;
    __builtin_amdgcn_s_setprio(1);
#pragma unroll
    for (int ii = 0; ii < 4; ++ii)
#pragma unroll
      for (int j = 0; j < 2; ++j)
#pragma unroll
        for (int ks = 0; ks < 2; ++ks)
          acc[ii][j] = __builtin_amdgcn_mfma_f32_16x16x32_f16(a[ii][ks], b[j][ks], acc[ii][j], 0, 0, 0);
    __builtin_amdgcn_s_setprio(0); SB0; PBAR;
    // ---------- phase 1: b(j2-3); stage A-h1 + B-h1 ----------
#pragma unroll
    for (int j = 2; j < 4; ++j) { b[j][0] = RDB(cb, j, 0); b[j][1] = RDB(cb, j, 1); }
    if (t >= 1 && t < 7) { STAGE_A(t + 1, 1); STAGE_B(t + 1, 1); }
    PBAR; LGKM0;
    __builtin_amdgcn_s_setprio(1);
#pragma unroll
    for (int ii = 0; ii < 4; ++ii)
#pragma unroll
      for (int j = 2; j < 4; ++j)
#pragma unroll
        for (int ks = 0; ks < 2; ++ks)
          acc[ii][j] = __builtin_amdgcn_mfma_f32_16x16x32_f16(a[ii][ks], b[j][ks], acc[ii][j], 0, 0, 0);
    __builtin_amdgcn_s_setprio(0); SB0; PBAR;
    // ---------- phase 2: a(i4-7) ----------
#pragma unroll
    for (int ii = 0; ii < 4; ++ii) { a[ii][0] = RDA(cb, 4 + ii, 0); a[ii][1] = RDA(cb, 4 + ii, 1); }
    PBAR; LGKM0;
    __builtin_amdgcn_s_setprio(1);
#pragma unroll
    for (int ii = 0; ii < 4; ++ii)
#pragma unroll
      for (int j = 0; j < 2; ++j)
#pragma unroll
        for (int ks = 0; ks < 2; ++ks)
          acc[4 + ii][j] = __builtin_amdgcn_mfma_f32_16x16x32_f16(a[ii][ks], b[j][ks], acc[4 + ii][j], 0, 0, 0);
    __builtin_amdgcn_s_setprio(0); SB0; PBAR;
    // ---------- phase 3: pure MFMA; boundary vmcnt drain (slack >= 2 phases) ----------
    __builtin_amdgcn_s_setprio(1);
#pragma unroll
    for (int ii = 0; ii < 4; ++ii)
#pragma unroll
      for (int j = 2; j < 4; ++j)
#pragma unroll
        for (int ks = 0; ks < 2; ++ks)
          acc[4 + ii][j] = __builtin_amdgcn_mfma_f32_16x16x32_f16(a[ii][ks], b[j][ks], acc[4 + ii][j], 0, 0, 0);
    __builtin_amdgcn_s_setprio(0); SB0;
    asm volatile("s_waitcnt vmcnt(0)" ::: "memory");
    PBAR;
  }
#undef STAGE_A
#undef STAGE_B
#undef RDA
#undef RDB

  // ---- epilogue: s = 0.5||c||^2 - dot ; per-query (min1,min2,argmin) over 256 codes
  float c2v[4];
#pragma unroll
  for (int j = 0; j < 4; ++j) c2v[j] = c2h[nb * 256 + nw * 64 + j * 16 + c];
#pragma unroll
  for (int i = 0; i < 8; ++i) {
    float m1[4], m2[4];
    int mc[4];
#pragma unroll
    for (int r = 0; r < 4; ++r) { m1[r] = 1e30f; m2[r] = 1e30f; mc[r] = 0; }
#pragma unroll
    for (int j = 0; j < 4; ++j) {
      int colb = nb * 256 + nw * 64 + j * 16 + c;
#pragma unroll
      for (int r = 0; r < 4; ++r) {
        float sv = c2v[j] - acc[i][j][r];
        float hi = fmaxf(sv, m1[r]);
        m2[r] = fminf(m2[r], hi);
        bool lt = sv < m1[r];
        m1[r] = lt ? sv : m1[r];
        mc[r] = lt ? colb : mc[r];
      }
    }
#pragma unroll
    for (int m = 1; m < 16; m <<= 1) {
#pragma unroll
      for (int r = 0; r < 4; ++r) {
        float o1 = __shfl_xor(m1[r], m);
        float o2 = __shfl_xor(m2[r], m);
        int   oc = __shfl_xor(mc[r], m);
        float hi = fmaxf(o1, m1[r]);
        m2[r] = fminf(fminf(m2[r], o2), hi);
        bool lt = o1 < m1[r];
        m1[r] = lt ? o1 : m1[r];
        mc[r] = lt ? oc : mc[r];
      }
    }
    if (c == 0) {
#pragma unroll
      for (int r = 0; r < 4; ++r) {
        int rb = mw * 128 + i * 16 + q * 4 + r;   // C/D row = q*4+reg; rb in 0..255
        red1[rb * 4 + nw] = m1[r];
        red2[rb * 4 + nw] = m2[r];
        redc[rb * 4 + nw] = mc[r];
      }
    }
  }
  __syncthreads();
  if (tid < 256) {
    float b1 = red1[tid * 4], b2 = red2[tid * 4];
    int bc = redc[tid * 4];
#pragma unroll
    for (int w = 1; w < 4; ++w) {
      float o1 = red1[tid * 4 + w], o2 = red2[tid * 4 + w];
      int oc = redc[tid * 4 + w];
      float hi = fmaxf(o1, b1);
      b2 = fminf(fminf(b2, o2), hi);
      if (o1 < b1) { b1 = o1; bc = oc; }
    }
    size_t qg = (size_t)(mb * 256 + tid) * 4 + nb;
    cand1[qg] = b1; cand2[qg] = b2; candc[qg] = bc;
  }
}

// ---------------- reduce: merge 4 candidates/query, flag near-ties ----------------
__global__ __launch_bounds__(256) void vq_reduce(const float4* __restrict__ c1,
                                                 const float4* __restrict__ c2,
                                                 const int4* __restrict__ cc,
                                                 int* __restrict__ idx,
                                                 int* __restrict__ list,
                                                 int* __restrict__ counter) {
  int qg = blockIdx.x * 256 + threadIdx.x;
  float4 a1 = c1[qg];
  float4 a2 = c2[qg];
  int4 ai = cc[qg];
  float m1[4] = {a1.x, a1.y, a1.z, a1.w};
  float m2[4] = {a2.x, a2.y, a2.z, a2.w};
  int mc[4] = {ai.x, ai.y, ai.z, ai.w};
  float g1 = m1[0], g2 = m2[0];
  int gc = mc[0];
#pragma unroll
  for (int k = 1; k < 4; ++k) {
    float hi = fmaxf(m1[k], g1);
    g2 = fminf(fminf(g2, m2[k]), hi);
    if (m1[k] < g1) { g1 = m1[k]; gc = mc[k]; }
  }
  idx[qg] = gc;
  if (g2 - g1 < TAU_S) { int p = atomicAdd(counter, 1); list[p] = qg; }
}

// ---------------- trans: cb [1024][512] -> cbT [512][1024] (fp32) ----------------
__global__ __launch_bounds__(256) void vq_trans(const float4* __restrict__ cb4,
                                                float4* __restrict__ cbT4) {
  __shared__ float t[64][65];
  const int bc = blockIdx.x >> 3, bk = blockIdx.x & 7;
  const int c0 = bc * 64, k0 = bk * 64;
  const int r = threadIdx.x >> 4, q4 = threadIdx.x & 15;
#pragma unroll
  for (int p = 0; p < 4; ++p) {
    int row = p * 16 + r;
    float4 v = cb4[(size_t)(c0 + row) * 128 + (k0 >> 2) + q4];
    t[row][q4 * 4 + 0] = v.x; t[row][q4 * 4 + 1] = v.y;
    t[row][q4 * 4 + 2] = v.z; t[row][q4 * 4 + 3] = v.w;
  }
  __syncthreads();
#pragma unroll
  for (int p = 0; p < 4; ++p) {
    int kk = p * 16 + r;
    float4 v = make_float4(t[q4 * 4 + 0][kk], t[q4 * 4 + 1][kk],
                           t[q4 * 4 + 2][kk], t[q4 * 4 + 3][kk]);
    cbT4[(size_t)(k0 + kk) * 256 + (c0 >> 2) + q4] = v;
  }
}

// ---------------- refine: exact fp64 re-scan, lane-per-4-codes ----------------
__global__ __launch_bounds__(256) void vq_refine(const float* __restrict__ x,
                                                 const float4* __restrict__ cbT4,
                                                 const double* __restrict__ c2d,
                                                 const int* __restrict__ list,
                                                 const int* __restrict__ counter,
                                                 int* __restrict__ idx) {
  __shared__ float xs[512];
  __shared__ double rv[4];
  __shared__ int rc[4];
  const int cnt = counter[0];
  const int tid = threadIdx.x, lane = tid & 63, wv = tid >> 6;
  for (int qi = blockIdx.x; qi < cnt; qi += gridDim.x) {
    const int query = list[qi];
    __syncthreads();
    xs[tid] = x[(size_t)query * KDIM + tid];
    xs[tid + 256] = x[(size_t)query * KDIM + tid + 256];
    __syncthreads();
    double a0 = 0, a1 = 0, a2 = 0, a3 = 0;
    const float4* xs4 = (const float4*)xs;
#pragma unroll 4
    for (int k4 = 0; k4 < 128; ++k4) {
      float4 xv = xs4[k4];
      float4 c0 = cbT4[(k4 * 4 + 0) * 256 + tid];
      float4 c1 = cbT4[(k4 * 4 + 1) * 256 + tid];
      float4 c2v = cbT4[(k4 * 4 + 2) * 256 + tid];
      float4 c3 = cbT4[(k4 * 4 + 3) * 256 + tid];
      a0 = fma((double)xv.x, (double)c0.x, a0);
      a1 = fma((double)xv.x, (double)c0.y, a1);
      a2 = fma((double)xv.x, (double)c0.z, a2);
      a3 = fma((double)xv.x, (double)c0.w, a3);
      a0 = fma((double)xv.y, (double)c1.x, a0);
      a1 = fma((double)xv.y, (double)c1.y, a1);
      a2 = fma((double)xv.y, (double)c1.z, a2);
      a3 = fma((double)xv.y, (double)c1.w, a3);
      a0 = fma((double)xv.z, (double)c2v.x, a0);
      a1 = fma((double)xv.z, (double)c2v.y, a1);
      a2 = fma((double)xv.z, (double)c2v.z, a2);
      a3 = fma((double)xv.z, (double)c2v.w, a3);
      a0 = fma((double)xv.w, (double)c3.x, a0);
      a1 = fma((double)xv.w, (double)c3.y, a1);
      a2 = fma((double)xv.w, (double)c3.z, a2);
      a3 = fma((double)xv.w, (double)c3.w, a3);
    }
    double best = c2d[tid * 4] - a0;
    int bc = tid * 4;
    double s1 = c2d[tid * 4 + 1] - a1;
    if (s1 < best) { best = s1; bc = tid * 4 + 1; }
    double s2 = c2d[tid * 4 + 2] - a2;
    if (s2 < best) { best = s2; bc = tid * 4 + 2; }
    double s3 = c2d[tid * 4 + 3] - a3;
    if (s3 < best) { best = s3; bc = tid * 4 + 3; }
#pragma unroll
    for (int m = 1; m < 64; m <<= 1) {
      double o = __shfl_xor(best, m);
      int oc = __shfl_xor(bc, m);
      if (o < best) { best = o; bc = oc; }
    }
    if (lane == 0) { rv[wv] = best; rc[wv] = bc; }
    __syncthreads();
    if (tid == 0) {
      double b = rv[0]; int bci = rc[0];
#pragma unroll
      for (int w = 1; w < 4; ++w)
        if (rv[w] < b) { b = rv[w]; bci = rc[w]; }
      idx[query] = bci;
    }
    __syncthreads();
  }
}

// ---------------- gather: out[q] = codebook[idx[q]] ----------------
__global__ __launch_bounds__(256) void vq_gather(const float* __restrict__ cb,
                                                 const int* __restrict__ idx,
                                                 float* __restrict__ out) {
  size_t i = (size_t)blockIdx.x * 256 + threadIdx.x;
  int qg = (int)(i >> 7), d = (int)(i & 127);
  ((float4*)out)[i] = ((const float4*)cb)[(size_t)idx[qg] * 128 + d];
}

extern "C" void kernel_launch(void* const* d_in, const int* in_sizes, int n_in,
                              void* d_out, int out_size, void* d_ws, size_t ws_size,
                              hipStream_t stream) {
  const float* x = (const float*)d_in[0];
  const float* cb = (const float*)d_in[1];
  float* out = (float*)d_out;
  char* ws = (char*)d_ws;
  if (ws_size < WS_NEED) {
    fprintf(stderr, "vq: ws_size %zu too small (need %llu)\n", ws_size,
            (unsigned long long)WS_NEED);
    return;
  }
  unsigned short* xh = (unsigned short*)(ws + WS_XH);
  unsigned short* cbh = (unsigned short*)(ws + WS_CBH);
  float* c2h = (float*)(ws + WS_C2H);
  double* c2d = (double*)(ws + WS_C2D);
  float* cand1 = (float*)(ws + WS_CAND1);
  float* cand2 = (float*)(ws + WS_CAND2);
  int* candc = (int*)(ws + WS_CANDC);
  float* cbT = (float*)(ws + WS_CBT);
  int* idx = (int*)(ws + WS_IDX);
  int* list = (int*)(ws + WS_LIST);
  int* counter = (int*)(ws + WS_CTR);

  hipMemsetAsync(counter, 0, 4, stream);
  vq_prep<<<256, 256, 0, stream>>>(cb, cbh, c2h, c2d);
  vq_convx<<<16384, 256, 0, stream>>>((const float4*)x, (int4*)xh);
  vq_main<<<1024, 512, 0, stream>>>(xh, cbh, c2h, cand1, cand2, candc);
  vq_reduce<<<256, 256, 0, stream>>>((const float4*)cand1, (const float4*)cand2,
                                     (const int4*)candc, idx, list, counter);
  vq_trans<<<128, 256, 0, stream>>>((const float4*)cb, (float4*)cbT);
  vq_refine<<<2048, 256, 0, stream>>>(x, (const float4*)cbT, c2d, list, counter, idx);
  vq_gather<<<32768, 256, 0, stream>>>(cb, idx, out);
}